// Round 2
// baseline (2666.934 us; speedup 1.0000x reference)
//
#include <hip/hip_runtime.h>
#include <stdint.h>
#include <stddef.h>

// NCA fused kernel for MI355X (gfx950).
//   p[b,y,x,o] = sum_{i,dy,dx} h[b,y+dy,x+dx,i] * conv_w[o,i,dx+1,dy+1]
// conv+fc_first fused into one GEMM via W1c[n][k=(tap,i)].
//
// This round: swapped-operand MFMA (D holds 4 contiguous hidden channels per
// lane -> packed ds_write_b64 epilogue), single in-place LDS buffer (32 KB)
// -> 4 blocks/CU.

typedef __bf16 bf16_t;
typedef bf16_t bf16x8 __attribute__((ext_vector_type(8)));
typedef bf16_t bf16x4 __attribute__((ext_vector_type(4)));
typedef float  f32x4  __attribute__((ext_vector_type(4)));

#define N_B     8
#define N_H     128
#define N_W     128
#define N_C     16
#define HID     256
#define N_L     3
#define N_STEPS 16
#define M_TILE  64
#define N_CELLS (N_B * N_H * N_W)
#define K1      160   // conv+fc1 fused K: 144 padded to 160

// XOR swizzle: breaks 512B-row-stride same-bank conflicts on ds_read_b128
// (apply identically on write and read; bijective within each 128B group)
__device__ __forceinline__ int swz(int row, int byteoff) {
  return byteoff ^ ((row & 7) << 4);
}

__global__ void prep_kernel(const float* __restrict__ conv_w,
                            const float* __restrict__ w_first,
                            const float* __restrict__ w_interim,
                            const float* __restrict__ w_last,
                            bf16_t* __restrict__ W1c,
                            bf16_t* __restrict__ Wi,
                            bf16_t* __restrict__ Wl) {
  const int tid = blockIdx.x * blockDim.x + threadIdx.x;
  const int nth = gridDim.x * blockDim.x;
  // W1c[n][k] = sum_o w_first[n][o] * conv_w[o][i][dx+1][dy+1], k=(tap)*16+i
  for (int idx = tid; idx < 256 * K1; idx += nth) {
    int n = idx / K1, k = idx - n * K1;
    float v = 0.f;
    if (k < 144) {
      int tap = k >> 4, i = k & 15;
      int dy = tap / 3 - 1, dx = tap % 3 - 1;
      for (int o = 0; o < 16; ++o)
        v += w_first[n * 16 + o] * conv_w[((o * 16 + i) * 3 + (dx + 1)) * 3 + (dy + 1)];
    }
    W1c[idx] = (bf16_t)v;
  }
  for (int idx = tid; idx < N_L * HID * HID; idx += nth)
    Wi[idx] = (bf16_t)w_interim[idx];
  for (int idx = tid; idx < N_C * HID; idx += nth)
    Wl[idx] = (bf16_t)w_last[idx];
}

// One MLP layer for the 64-row tile, IN-PLACE in buf:
//   buf <- relu(buf @ Wg^T + bias), N=256, each wave owns a 64-wide N slice.
// Swapped MFMA: D = mfma(Wfrag, actfrag) => D[i=n][j=cell];
// lane holds cell (mt*16 + lane&15), channels n = nbase+nt*16+4*(lane>>4)+j
// -> packed b64 write of 4 contiguous bf16.
// Contains an internal __syncthreads between consume and in-place write.
template <int K>
__device__ __forceinline__ void mlp_layer(uint8_t* __restrict__ buf,
                                          const bf16_t* __restrict__ Wg,
                                          const float* __restrict__ bias,
                                          int lane, int wid) {
  const int lr = lane & 15;
  const int lk = lane >> 4;
  const int nbase = wid * 64;
  f32x4 acc[4][4];
#pragma unroll
  for (int nt = 0; nt < 4; ++nt) {
    f32x4 binit = *(const f32x4*)(bias + nbase + nt * 16 + lk * 4);
#pragma unroll
    for (int mt = 0; mt < 4; ++mt) acc[mt][nt] = binit;
  }
#pragma unroll
  for (int kk = 0; kk < K / 32; ++kk) {
    bf16x8 a[4], bfr[4];
    const int kb = kk * 64 + lk * 16;  // byte offset of this lane's 8 bf16
#pragma unroll
    for (int mt = 0; mt < 4; ++mt) {
      int row = mt * 16 + lr;
      a[mt] = *(const bf16x8*)(buf + row * 512 + swz(row, kb));
    }
#pragma unroll
    for (int nt = 0; nt < 4; ++nt) {
      int col = nbase + nt * 16 + lr;
      bfr[nt] = *(const bf16x8*)(Wg + col * K + kk * 32 + lk * 8);
    }
#pragma unroll
    for (int mt = 0; mt < 4; ++mt)
#pragma unroll
      for (int nt = 0; nt < 4; ++nt)
        acc[mt][nt] = __builtin_amdgcn_mfma_f32_16x16x32_bf16(bfr[nt], a[mt], acc[mt][nt], 0, 0, 0);
  }
  __syncthreads();  // input tile fully consumed by ALL waves; safe to overwrite
#pragma unroll
  for (int mt = 0; mt < 4; ++mt)
#pragma unroll
    for (int nt = 0; nt < 4; ++nt) {
      bf16x4 w;
#pragma unroll
      for (int j = 0; j < 4; ++j) w[j] = (bf16_t)fmaxf(acc[mt][nt][j], 0.f);
      int row = mt * 16 + lr;                      // cell
      int nb = (nbase + nt * 16 + lk * 4) * 2;     // byte offset of 4 channels
      *(bf16x4*)(buf + row * 512 + swz(row, nb)) = w;
    }
}

__global__ __launch_bounds__(256, 4)
void nca_step_kernel(const float* __restrict__ hsrc, float* __restrict__ hdst,
                     const bf16_t* __restrict__ W1c, const bf16_t* __restrict__ Wi,
                     const bf16_t* __restrict__ Wl,
                     const float* __restrict__ b_first,
                     const float* __restrict__ b_interim) {
  __shared__ __align__(16) uint8_t buf[M_TILE * 512];

  const int t = threadIdx.x;
  const int lane = t & 63;
  const int wid = t >> 6;
  const int cell0 = blockIdx.x * M_TILE;
  const int b = cell0 >> 14;          // /(128*128)
  const int rem = cell0 & 16383;
  const int y = rem >> 7;
  const int x0 = rem & 127;           // 0 or 64; a tile never crosses a row

  // ---- Phase A: build bf16 patch[64][160] into buf (rows=cells, k=tap*16+i)
  {
    const int m = t & 63;
    const int q = t >> 6;
    const int x = x0 + m;
#pragma unroll
    for (int j = 0; j < 36; ++j) {
      int k = q * 36 + j;
      int tap = k >> 4, i = k & 15;
      int dy = tap / 3 - 1, dx = tap % 3 - 1;
      int yy = y + dy, xx = x + dx;
      float v = 0.f;
      if ((unsigned)yy < (unsigned)N_H && (unsigned)xx < (unsigned)N_W)
        v = hsrc[((b * N_H + yy) * N_W + xx) * N_C + i];
      *(bf16_t*)(buf + m * 512 + swz(m, 2 * k)) = (bf16_t)v;
    }
    // zero k = 144..159 (pad region read by last k-step)
#pragma unroll
    for (int j = 0; j < 4; ++j) {
      int k = 144 + q * 4 + j;
      *(bf16_t*)(buf + m * 512 + swz(m, 2 * k)) = (bf16_t)0.f;
    }
  }
  __syncthreads();

  mlp_layer<K1>(buf, W1c, b_first, lane, wid);               // conv+fc1
  __syncthreads();
  mlp_layer<HID>(buf, Wi + 0 * HID * HID, b_interim + 0 * HID, lane, wid);
  __syncthreads();
  mlp_layer<HID>(buf, Wi + 1 * HID * HID, b_interim + 1 * HID, lane, wid);
  __syncthreads();
  mlp_layer<HID>(buf, Wi + 2 * HID * HID, b_interim + 2 * HID, lane, wid);
  __syncthreads();

  // ---- Last layer: out[64][16] = act @ w_last^T ; residual in f32 (swapped:
  // lane holds cell wid*16+lr, channels 4*lk..4*lk+3 -> float4 global I/O)
  {
    const int lr = lane & 15;
    const int lk = lane >> 4;
    f32x4 acc = {0.f, 0.f, 0.f, 0.f};
#pragma unroll
    for (int kk = 0; kk < HID / 32; ++kk) {
      int row = wid * 16 + lr;
      bf16x8 a = *(const bf16x8*)(buf + row * 512 + swz(row, kk * 64 + lk * 16));
      bf16x8 bb = *(const bf16x8*)(Wl + lr * HID + kk * 32 + lk * 8);
      acc = __builtin_amdgcn_mfma_f32_16x16x32_bf16(bb, a, acc, 0, 0, 0);
    }
    const int cell = cell0 + wid * 16 + lr;
    const int gi = cell * N_C + lk * 4;
    f32x4 r = *(const f32x4*)(hsrc + gi);
#pragma unroll
    for (int j = 0; j < 4; ++j) r[j] += acc[j];
    *(f32x4*)(hdst + gi) = r;
  }
}

extern "C" void kernel_launch(void* const* d_in, const int* in_sizes, int n_in,
                              void* d_out, int out_size, void* d_ws, size_t ws_size,
                              hipStream_t stream) {
  const float* x         = (const float*)d_in[0];
  const float* conv_w    = (const float*)d_in[1];
  const float* w_first   = (const float*)d_in[2];
  const float* b_first   = (const float*)d_in[3];
  const float* w_interim = (const float*)d_in[4];
  const float* b_interim = (const float*)d_in[5];
  const float* w_last    = (const float*)d_in[6];
  // d_in[7] = steps (scalar, == 16 per reference; fixed at compile time)

  float* xfinal = (float*)d_out;
  float* hist   = xfinal + (size_t)N_CELLS * N_C;  // 17 slots of h-state

  bf16_t* W1c = (bf16_t*)d_ws;          // [256][160]
  bf16_t* Wi  = W1c + 256 * K1;         // [3][256][256]
  bf16_t* Wl  = Wi + N_L * HID * HID;   // [16][256]   (~483 KB total in ws)

  prep_kernel<<<64, 256, 0, stream>>>(conv_w, w_first, w_interim, w_last, W1c, Wi, Wl);
  hipMemcpyAsync(hist, x, (size_t)N_CELLS * N_C * sizeof(float),
                 hipMemcpyDeviceToDevice, stream);
  for (int s = 0; s < N_STEPS; ++s)
    nca_step_kernel<<<N_CELLS / M_TILE, 256, 0, stream>>>(
        hist + (size_t)s * N_CELLS * N_C, hist + (size_t)(s + 1) * N_CELLS * N_C,
        W1c, Wi, Wl, b_first, b_interim);
  hipMemcpyAsync(xfinal, hist + (size_t)N_STEPS * N_CELLS * N_C,
                 (size_t)N_CELLS * N_C * sizeof(float),
                 hipMemcpyDeviceToDevice, stream);
}

// Round 3
// 2451.739 us; speedup vs baseline: 1.0878x; 1.0878x over previous
//
#include <hip/hip_runtime.h>
#include <stdint.h>
#include <stddef.h>

// NCA fused kernel for MI355X (gfx950).
//   p[b,y,x,o] = sum_{i,dy,dx} h[b,y+dy,x+dx,i] * conv_w[o,i,dx+1,dy+1]
// conv+fc_first fused into one GEMM via W1c[n][k=(tap,i)].
//
// R3: 512-thread blocks / 8 waves, each wave owns a 64x32 N-slice
// (acc = 32 VGPR/lane, no spill), single in-place 32KB LDS buffer,
// __launch_bounds__(512,4) -> 2 blocks/CU = 16 waves/CU.
// R2 lesson: (256,4) budget=128 VGPR forced scratch spill -> 150MB/step
// of HBM traffic. Reduce register need structurally, not via allocator.

typedef __bf16 bf16_t;
typedef bf16_t bf16x8 __attribute__((ext_vector_type(8)));
typedef bf16_t bf16x4 __attribute__((ext_vector_type(4)));
typedef float  f32x4  __attribute__((ext_vector_type(4)));

#define N_B     8
#define N_H     128
#define N_W     128
#define N_C     16
#define HID     256
#define N_L     3
#define N_STEPS 16
#define M_TILE  64
#define THREADS 512
#define N_CELLS (N_B * N_H * N_W)
#define K1      160   // conv+fc1 fused K: 144 padded to 160

// XOR swizzle: breaks 512B-row-stride same-bank conflicts on ds_read_b128
// (apply identically on write and read; bijective within each 128B group)
__device__ __forceinline__ int swz(int row, int byteoff) {
  return byteoff ^ ((row & 7) << 4);
}

__global__ void prep_kernel(const float* __restrict__ conv_w,
                            const float* __restrict__ w_first,
                            const float* __restrict__ w_interim,
                            const float* __restrict__ w_last,
                            bf16_t* __restrict__ W1c,
                            bf16_t* __restrict__ Wi,
                            bf16_t* __restrict__ Wl) {
  const int tid = blockIdx.x * blockDim.x + threadIdx.x;
  const int nth = gridDim.x * blockDim.x;
  // W1c[n][k] = sum_o w_first[n][o] * conv_w[o][i][dx+1][dy+1], k=(tap)*16+i
  for (int idx = tid; idx < 256 * K1; idx += nth) {
    int n = idx / K1, k = idx - n * K1;
    float v = 0.f;
    if (k < 144) {
      int tap = k >> 4, i = k & 15;
      int dy = tap / 3 - 1, dx = tap % 3 - 1;
      for (int o = 0; o < 16; ++o)
        v += w_first[n * 16 + o] * conv_w[((o * 16 + i) * 3 + (dx + 1)) * 3 + (dy + 1)];
    }
    W1c[idx] = (bf16_t)v;
  }
  for (int idx = tid; idx < N_L * HID * HID; idx += nth)
    Wi[idx] = (bf16_t)w_interim[idx];
  for (int idx = tid; idx < N_C * HID; idx += nth)
    Wl[idx] = (bf16_t)w_last[idx];
}

// One MLP layer for the 64-row tile, IN-PLACE in buf:
//   buf <- relu(buf @ Wg^T + bias), N=256; 8 waves, each owns a 32-wide
// N-slice (nbase = wid*32). Swapped MFMA: D = mfma(Wfrag, actfrag) =>
// lane holds cell (mt*16 + lane&15), channels n = nbase+nt*16+4*(lane>>4)+j
// -> packed b64 write of 4 contiguous bf16.
// Contains an internal __syncthreads between consume and in-place write.
template <int K>
__device__ __forceinline__ void mlp_layer(uint8_t* __restrict__ buf,
                                          const bf16_t* __restrict__ Wg,
                                          const float* __restrict__ bias,
                                          int lane, int wid) {
  const int lr = lane & 15;
  const int lk = lane >> 4;
  const int nbase = wid * 32;
  f32x4 acc[4][2];
#pragma unroll
  for (int nt = 0; nt < 2; ++nt) {
    f32x4 binit = *(const f32x4*)(bias + nbase + nt * 16 + lk * 4);
#pragma unroll
    for (int mt = 0; mt < 4; ++mt) acc[mt][nt] = binit;
  }
#pragma unroll
  for (int kk = 0; kk < K / 32; ++kk) {
    bf16x8 a[4], bfr[2];
    const int kb = kk * 64 + lk * 16;  // byte offset of this lane's 8 bf16
#pragma unroll
    for (int mt = 0; mt < 4; ++mt) {
      int row = mt * 16 + lr;
      a[mt] = *(const bf16x8*)(buf + row * 512 + swz(row, kb));
    }
#pragma unroll
    for (int nt = 0; nt < 2; ++nt) {
      int col = nbase + nt * 16 + lr;
      bfr[nt] = *(const bf16x8*)(Wg + col * K + kk * 32 + lk * 8);
    }
#pragma unroll
    for (int mt = 0; mt < 4; ++mt)
#pragma unroll
      for (int nt = 0; nt < 2; ++nt)
        acc[mt][nt] = __builtin_amdgcn_mfma_f32_16x16x32_bf16(bfr[nt], a[mt], acc[mt][nt], 0, 0, 0);
  }
  __syncthreads();  // input tile fully consumed by ALL waves; safe to overwrite
#pragma unroll
  for (int mt = 0; mt < 4; ++mt)
#pragma unroll
    for (int nt = 0; nt < 2; ++nt) {
      bf16x4 w;
#pragma unroll
      for (int j = 0; j < 4; ++j) w[j] = (bf16_t)fmaxf(acc[mt][nt][j], 0.f);
      int row = mt * 16 + lr;                      // cell
      int nb = (nbase + nt * 16 + lk * 4) * 2;     // byte offset of 4 channels
      *(bf16x4*)(buf + row * 512 + swz(row, nb)) = w;
    }
}

__global__ __launch_bounds__(THREADS, 4)
void nca_step_kernel(const float* __restrict__ hsrc, float* __restrict__ hdst,
                     const bf16_t* __restrict__ W1c, const bf16_t* __restrict__ Wi,
                     const bf16_t* __restrict__ Wl,
                     const float* __restrict__ b_first,
                     const float* __restrict__ b_interim) {
  __shared__ __align__(16) uint8_t buf[M_TILE * 512];

  const int t = threadIdx.x;
  const int lane = t & 63;
  const int wid = t >> 6;
  const int cell0 = blockIdx.x * M_TILE;
  const int b = cell0 >> 14;          // /(128*128)
  const int rem = cell0 & 16383;
  const int y = rem >> 7;
  const int x0 = rem & 127;           // 0 or 64; a tile never crosses a row

  // ---- Phase A: build bf16 patch[64][160] into buf (rows=cells, k=tap*16+i)
  // 512 threads: row m = t&63, k-chunk q = t>>6 covers k = q*20 .. q*20+19
  {
    const int m = t & 63;
    const int q = t >> 6;
    const int x = x0 + m;
#pragma unroll
    for (int j = 0; j < 20; ++j) {
      int k = q * 20 + j;
      float v = 0.f;
      if (k < 144) {
        int tap = k >> 4, i = k & 15;
        int dy = tap / 3 - 1, dx = tap % 3 - 1;
        int yy = y + dy, xx = x + dx;
        if ((unsigned)yy < (unsigned)N_H && (unsigned)xx < (unsigned)N_W)
          v = hsrc[((b * N_H + yy) * N_W + xx) * N_C + i];
      }
      *(bf16_t*)(buf + m * 512 + swz(m, 2 * k)) = (bf16_t)v;
    }
  }
  __syncthreads();

  mlp_layer<K1>(buf, W1c, b_first, lane, wid);               // conv+fc1
  __syncthreads();
  mlp_layer<HID>(buf, Wi + 0 * HID * HID, b_interim + 0 * HID, lane, wid);
  __syncthreads();
  mlp_layer<HID>(buf, Wi + 1 * HID * HID, b_interim + 1 * HID, lane, wid);
  __syncthreads();
  mlp_layer<HID>(buf, Wi + 2 * HID * HID, b_interim + 2 * HID, lane, wid);
  __syncthreads();

  // ---- Last layer: out[64][16] = act @ w_last^T ; residual in f32 (swapped:
  // lane holds cell wid*16+lr, channels 4*lk..4*lk+3 -> float4 global I/O)
  // Only waves 0-3 needed (64 cells / 16 per wave); no barriers below.
  if (wid < 4) {
    const int lr = lane & 15;
    const int lk = lane >> 4;
    f32x4 acc = {0.f, 0.f, 0.f, 0.f};
#pragma unroll
    for (int kk = 0; kk < HID / 32; ++kk) {
      int row = wid * 16 + lr;
      bf16x8 a = *(const bf16x8*)(buf + row * 512 + swz(row, kk * 64 + lk * 16));
      bf16x8 bb = *(const bf16x8*)(Wl + lr * HID + kk * 32 + lk * 8);
      acc = __builtin_amdgcn_mfma_f32_16x16x32_bf16(bb, a, acc, 0, 0, 0);
    }
    const int cell = cell0 + wid * 16 + lr;
    const int gi = cell * N_C + lk * 4;
    f32x4 r = *(const f32x4*)(hsrc + gi);
#pragma unroll
    for (int j = 0; j < 4; ++j) r[j] += acc[j];
    *(f32x4*)(hdst + gi) = r;
  }
}

extern "C" void kernel_launch(void* const* d_in, const int* in_sizes, int n_in,
                              void* d_out, int out_size, void* d_ws, size_t ws_size,
                              hipStream_t stream) {
  const float* x         = (const float*)d_in[0];
  const float* conv_w    = (const float*)d_in[1];
  const float* w_first   = (const float*)d_in[2];
  const float* b_first   = (const float*)d_in[3];
  const float* w_interim = (const float*)d_in[4];
  const float* b_interim = (const float*)d_in[5];
  const float* w_last    = (const float*)d_in[6];
  // d_in[7] = steps (scalar, == 16 per reference; fixed at compile time)

  float* xfinal = (float*)d_out;
  float* hist   = xfinal + (size_t)N_CELLS * N_C;  // 17 slots of h-state

  bf16_t* W1c = (bf16_t*)d_ws;          // [256][160]
  bf16_t* Wi  = W1c + 256 * K1;         // [3][256][256]
  bf16_t* Wl  = Wi + N_L * HID * HID;   // [16][256]   (~483 KB total in ws)

  prep_kernel<<<64, 256, 0, stream>>>(conv_w, w_first, w_interim, w_last, W1c, Wi, Wl);
  hipMemcpyAsync(hist, x, (size_t)N_CELLS * N_C * sizeof(float),
                 hipMemcpyDeviceToDevice, stream);
  for (int s = 0; s < N_STEPS; ++s)
    nca_step_kernel<<<N_CELLS / M_TILE, THREADS, 0, stream>>>(
        hist + (size_t)s * N_CELLS * N_C, hist + (size_t)(s + 1) * N_CELLS * N_C,
        W1c, Wi, Wl, b_first, b_interim);
  hipMemcpyAsync(xfinal, hist + (size_t)N_STEPS * N_CELLS * N_C,
                 (size_t)N_CELLS * N_C * sizeof(float),
                 hipMemcpyDeviceToDevice, stream);
}

// Round 4
// 1071.339 us; speedup vs baseline: 2.4893x; 2.2885x over previous
//
#include <hip/hip_runtime.h>
#include <stdint.h>
#include <stddef.h>

// NCA fused kernel for MI355X (gfx950).
//   p[b,y,x,o] = sum_{i,dy,dx} h[b,y+dy,x+dx,i] * conv_w[o,i,dx+1,dy+1]
// conv+fc_first fused into one GEMM via W1c[n][k=(tap,i)].
//
// R4: 128 cells/block as 2 LDS tiles sharing one weight-fragment stream
// (weight loads per cell halved, 2x ILP between barriers, barrier cost per
// cell halved); weights pre-shuffled in prep to fragment order so the main
// loop's weight load is one lane-linear coalesced dwordx4; phase A
// vectorized (f32x4 loads -> packed bf16x4 LDS writes).
// R2 lesson: keep live regs ~<=110 under (512,4)'s 128 budget. acc=64.

typedef __bf16 bf16_t;
typedef bf16_t bf16x8 __attribute__((ext_vector_type(8)));
typedef bf16_t bf16x4 __attribute__((ext_vector_type(4)));
typedef float  f32x4  __attribute__((ext_vector_type(4)));

#define N_B     8
#define N_H     128
#define N_W     128
#define N_C     16
#define HID     256
#define N_L     3
#define N_STEPS 16
#define M_TILE  128
#define THREADS 512
#define N_CELLS (N_B * N_H * N_W)
#define K1      160   // conv+fc1 fused K: 144 padded to 160
#define KK1     5     // K1/32
#define KKH     8     // HID/32

// XOR swizzle: breaks 512B-row-stride same-bank conflicts on LDS access
// (apply identically on write and read; bijective within each 128B group)
__device__ __forceinline__ int swz(int row, int byteoff) {
  return byteoff ^ ((row & 7) << 4);
}

// Weights are pre-shuffled into MFMA fragment order:
//   idx = (((wid*KK + kk)*2 + nt)*64 + lane)*8 + e
// holding W[col][k], col = wid*32 + nt*16 + (lane&15),
//                    k   = kk*32 + (lane>>4)*8 + e.
__global__ void prep_kernel(const float* __restrict__ conv_w,
                            const float* __restrict__ w_first,
                            const float* __restrict__ w_interim,
                            const float* __restrict__ w_last,
                            bf16_t* __restrict__ W1c_lin,
                            bf16_t* __restrict__ Wi_lin,
                            bf16_t* __restrict__ Wl_lin) {
  const int tid = blockIdx.x * blockDim.x + threadIdx.x;
  const int nth = gridDim.x * blockDim.x;
  // fused conv+fc1 weights, K1=160 (k>=144 zero pad)
  for (int idx = tid; idx < 256 * K1; idx += nth) {
    int e = idx & 7, lane = (idx >> 3) & 63, nt = (idx >> 9) & 1, r = idx >> 10;
    int kk = r % KK1, wid = r / KK1;
    int col = wid * 32 + nt * 16 + (lane & 15);
    int k = kk * 32 + (lane >> 4) * 8 + e;
    float v = 0.f;
    if (k < 144) {
      int tap = k >> 4, i = k & 15;
      int dy = tap / 3 - 1, dx = tap % 3 - 1;
      for (int o = 0; o < 16; ++o)
        v += w_first[col * 16 + o] * conv_w[((o * 16 + i) * 3 + (dx + 1)) * 3 + (dy + 1)];
    }
    W1c_lin[idx] = (bf16_t)v;
  }
  for (int idx = tid; idx < N_L * HID * HID; idx += nth) {
    int l = idx / (HID * HID), idx2 = idx % (HID * HID);
    int e = idx2 & 7, lane = (idx2 >> 3) & 63, nt = (idx2 >> 9) & 1, r = idx2 >> 10;
    int kk = r & 7, wid = r >> 3;
    int col = wid * 32 + nt * 16 + (lane & 15);
    int k = kk * 32 + (lane >> 4) * 8 + e;
    Wi_lin[idx] = (bf16_t)w_interim[(l * HID + col) * HID + k];
  }
  // last layer: idx = (kk*64+lane)*8+e -> Wl[col=lane&15][k]
  for (int idx = tid; idx < N_C * HID; idx += nth) {
    int e = idx & 7, lane = (idx >> 3) & 63, kk = idx >> 9;
    int col = lane & 15;
    int k = kk * 32 + (lane >> 4) * 8 + e;
    Wl_lin[idx] = (bf16_t)w_last[col * HID + k];
  }
}

// One MLP layer applied IN-PLACE to BOTH 64-row tiles:
//   buf* <- relu(buf* @ W^T + bias), N=256; 8 waves, each owns a 32-wide
// N-slice. Swapped MFMA: D = mfma(Wfrag, actfrag); lane holds cell
// (mt*16+lane&15), channels n = wid*32+nt*16+4*(lane>>4)+j -> packed b64
// write. One weight-fragment load feeds both tiles' MFMAs.
// Contains an internal __syncthreads between consume and in-place write.
template <int KK>
__device__ __forceinline__ void mlp2(uint8_t* __restrict__ b0,
                                     uint8_t* __restrict__ b1,
                                     const bf16_t* __restrict__ Wlin,
                                     const float* __restrict__ bias,
                                     int lane, int wid) {
  const int lr = lane & 15;
  const int lk = lane >> 4;
  const int nbase = wid * 32;
  const bf16x8* __restrict__ wfrag = (const bf16x8*)Wlin + (wid * KK) * 2 * 64 + lane;
  f32x4 acc[2][4][2];
#pragma unroll
  for (int nt = 0; nt < 2; ++nt) {
    f32x4 binit = *(const f32x4*)(bias + nbase + nt * 16 + lk * 4);
#pragma unroll
    for (int mt = 0; mt < 4; ++mt) { acc[0][mt][nt] = binit; acc[1][mt][nt] = binit; }
  }
#pragma unroll
  for (int kk = 0; kk < KK; ++kk) {
    bf16x8 bfr[2];
#pragma unroll
    for (int nt = 0; nt < 2; ++nt) bfr[nt] = wfrag[(kk * 2 + nt) * 64];
    const int kb = kk * 64 + lk * 16;
    bf16x8 a[4];
#pragma unroll
    for (int mt = 0; mt < 4; ++mt) {
      int row = mt * 16 + lr;
      a[mt] = *(const bf16x8*)(b0 + row * 512 + swz(row, kb));
    }
#pragma unroll
    for (int mt = 0; mt < 4; ++mt)
#pragma unroll
      for (int nt = 0; nt < 2; ++nt)
        acc[0][mt][nt] = __builtin_amdgcn_mfma_f32_16x16x32_bf16(bfr[nt], a[mt], acc[0][mt][nt], 0, 0, 0);
#pragma unroll
    for (int mt = 0; mt < 4; ++mt) {
      int row = mt * 16 + lr;
      a[mt] = *(const bf16x8*)(b1 + row * 512 + swz(row, kb));
    }
#pragma unroll
    for (int mt = 0; mt < 4; ++mt)
#pragma unroll
      for (int nt = 0; nt < 2; ++nt)
        acc[1][mt][nt] = __builtin_amdgcn_mfma_f32_16x16x32_bf16(bfr[nt], a[mt], acc[1][mt][nt], 0, 0, 0);
  }
  __syncthreads();  // both tiles fully consumed by ALL waves; safe to overwrite
#pragma unroll
  for (int tile = 0; tile < 2; ++tile) {
    uint8_t* tb = tile ? b1 : b0;
#pragma unroll
    for (int mt = 0; mt < 4; ++mt)
#pragma unroll
      for (int nt = 0; nt < 2; ++nt) {
        bf16x4 w;
#pragma unroll
        for (int j = 0; j < 4; ++j) w[j] = (bf16_t)fmaxf(acc[tile][mt][nt][j], 0.f);
        int row = mt * 16 + lr;                      // cell
        int nb = (nbase + nt * 16 + lk * 4) * 2;     // byte offset of 4 channels
        *(bf16x4*)(tb + row * 512 + swz(row, nb)) = w;
      }
  }
}

__global__ __launch_bounds__(THREADS, 4)
void nca_step_kernel(const float* __restrict__ hsrc, float* __restrict__ hdst,
                     const bf16_t* __restrict__ W1c_lin, const bf16_t* __restrict__ Wi_lin,
                     const bf16_t* __restrict__ Wl_lin,
                     const float* __restrict__ b_first,
                     const float* __restrict__ b_interim) {
  __shared__ __align__(16) uint8_t buf[2][64 * 512];   // 64 KB, 2 tiles

  const int t = threadIdx.x;
  const int lane = t & 63;
  const int wid = t >> 6;
  const int by = blockIdx.x;      // block = one image row: 1024 = 8 b x 128 y
  const int b = by >> 7;
  const int y = by & 127;

  // ---- Phase A: patch[128][160] as 2 tiles of [64][512B] (k = tap*16 + i)
  // thread t: cell m = t&127 (x coordinate), k4-chunk group q = t>>7 (0..3)
  {
    const int m = t & 127;
    const int q = t >> 7;
    uint8_t* tb = buf[m >> 6];
    const int row = m & 63;
#pragma unroll
    for (int jj = 0; jj < 9; ++jj) {
      int k4 = q * 9 + jj;             // 0..35 real chunks (k = 4*k4)
      int tap = k4 >> 2, i0 = (k4 & 3) * 4;
      int dy = tap / 3 - 1, dx = tap % 3 - 1;
      int yy = y + dy, xx = m + dx;
      f32x4 v = {0.f, 0.f, 0.f, 0.f};
      if ((unsigned)yy < (unsigned)N_H && (unsigned)xx < (unsigned)N_W)
        v = *(const f32x4*)(hsrc + ((b * N_H + yy) * N_W + xx) * N_C + i0);
      bf16x4 w;
#pragma unroll
      for (int j = 0; j < 4; ++j) w[j] = (bf16_t)v[j];
      *(bf16x4*)(tb + row * 512 + swz(row, 8 * k4)) = w;
    }
    // zero pad k4 = 36..39 (k = 144..159)
    bf16x4 z;
#pragma unroll
    for (int j = 0; j < 4; ++j) z[j] = (bf16_t)0.f;
    int k4p = 36 + q;
    *(bf16x4*)(tb + row * 512 + swz(row, 8 * k4p)) = z;
  }
  __syncthreads();

  mlp2<KK1>(buf[0], buf[1], W1c_lin, b_first, lane, wid);   // conv+fc1
  __syncthreads();
  mlp2<KKH>(buf[0], buf[1], Wi_lin + 0 * HID * HID, b_interim + 0 * HID, lane, wid);
  __syncthreads();
  mlp2<KKH>(buf[0], buf[1], Wi_lin + 1 * HID * HID, b_interim + 1 * HID, lane, wid);
  __syncthreads();
  mlp2<KKH>(buf[0], buf[1], Wi_lin + 2 * HID * HID, b_interim + 2 * HID, lane, wid);
  __syncthreads();

  // ---- Last layer: out[128][16] = act @ w_last^T ; residual in f32.
  // wave w handles cells w*16..w*16+15 (tile = w>>2, rows (w&3)*16+lr);
  // lane holds cell, channels 4*lk..4*lk+3 -> float4 global I/O.
  {
    const int lr = lane & 15;
    const int lk = lane >> 4;
    const uint8_t* tb = buf[wid >> 2];
    const int rb = (wid & 3) * 16;
    const bf16x8* __restrict__ wl = (const bf16x8*)Wl_lin + lane;
    f32x4 acc = {0.f, 0.f, 0.f, 0.f};
#pragma unroll
    for (int kk = 0; kk < KKH; ++kk) {
      int row = rb + lr;
      bf16x8 a = *(const bf16x8*)(tb + row * 512 + swz(row, kk * 64 + lk * 16));
      bf16x8 bb = wl[kk * 64];
      acc = __builtin_amdgcn_mfma_f32_16x16x32_bf16(bb, a, acc, 0, 0, 0);
    }
    const int cell = by * M_TILE + wid * 16 + lr;
    const int gi = cell * N_C + lk * 4;
    f32x4 r = *(const f32x4*)(hsrc + gi);
#pragma unroll
    for (int j = 0; j < 4; ++j) r[j] += acc[j];
    *(f32x4*)(hdst + gi) = r;
  }
}

extern "C" void kernel_launch(void* const* d_in, const int* in_sizes, int n_in,
                              void* d_out, int out_size, void* d_ws, size_t ws_size,
                              hipStream_t stream) {
  const float* x         = (const float*)d_in[0];
  const float* conv_w    = (const float*)d_in[1];
  const float* w_first   = (const float*)d_in[2];
  const float* b_first   = (const float*)d_in[3];
  const float* w_interim = (const float*)d_in[4];
  const float* b_interim = (const float*)d_in[5];
  const float* w_last    = (const float*)d_in[6];
  // d_in[7] = steps (scalar, == 16 per reference; fixed at compile time)

  float* xfinal = (float*)d_out;
  float* hist   = xfinal + (size_t)N_CELLS * N_C;  // 17 slots of h-state

  bf16_t* W1c_lin = (bf16_t*)d_ws;            // 256*160
  bf16_t* Wi_lin  = W1c_lin + 256 * K1;       // 3*256*256
  bf16_t* Wl_lin  = Wi_lin + N_L * HID * HID; // 16*256   (~483 KB total)

  prep_kernel<<<64, 256, 0, stream>>>(conv_w, w_first, w_interim, w_last,
                                      W1c_lin, Wi_lin, Wl_lin);
  hipMemcpyAsync(hist, x, (size_t)N_CELLS * N_C * sizeof(float),
                 hipMemcpyDeviceToDevice, stream);
  for (int s = 0; s < N_STEPS; ++s)
    nca_step_kernel<<<N_CELLS / M_TILE, THREADS, 0, stream>>>(
        hist + (size_t)s * N_CELLS * N_C, hist + (size_t)(s + 1) * N_CELLS * N_C,
        W1c_lin, Wi_lin, Wl_lin, b_first, b_interim);
  hipMemcpyAsync(xfinal, hist + (size_t)N_STEPS * N_CELLS * N_C,
                 (size_t)N_CELLS * N_C * sizeof(float),
                 hipMemcpyDeviceToDevice, stream);
}